// Round 1
// baseline (1091.573 us; speedup 1.0000x reference)
//
#include <hip/hip_runtime.h>
#include <hip/hip_bf16.h>

// PSWarpHead: conv3x3(256->28,SAME) + BN + ReLU + conv1x1(28->28) +
// rotated-grid position-sensitive bilinear sampling, mean over 28 positions.
// B=4, Cin=256, H=200, W=176, P=28, N=2048. Output: 8192 scores (bf16 or f32).
//
// Round 1: correctness-first vector (non-MFMA) pipeline with runtime dtype
// self-detection (harness appears to bf16-ify tensors; reference says f32).
// detect: bn_gamma[0]==1.0 -> first ushort 0x3F80 iff bf16.

#define WDIM 176
#define HDIM 200
#define HWDIM 35200
#define CIN 256
#define PDIM 28
#define NBOX 2048

__device__ __forceinline__ bool detect_bf16(const void* gamma) {
    return ((const unsigned short*)gamma)[0] == 0x3F80u;
}

template<bool BF>
__device__ __forceinline__ float ldf(const void* p, long i) {
    if (BF) return __bfloat162float(((const __hip_bfloat16*)p)[i]);
    else    return ((const float*)p)[i];
}

// ---------------- prep: weight relayout (fp32) + BN fold ----------------
// wf1[c*252 + p*9 + t] = w1[p*2304 + c*9 + t]   (t = i*3+j)
template<bool BF>
__global__ void prep_kernel(const void* w1, const void* w2,
                            const void* g, const void* bt, const void* mn, const void* vr,
                            float* wf1, float* w2f, float* scale, float* shift) {
    if (detect_bf16(g) != BF) return;
    int idx = blockIdx.x * 256 + threadIdx.x;
    if (idx < 64512) {
        int c = idx / 252;
        int r = idx - c * 252;
        int p = r / 9;
        int t = r - p * 9;
        wf1[idx] = ldf<BF>(w1, (long)p * 2304 + c * 9 + t);
    } else if (idx < 64512 + 784) {
        int i = idx - 64512;
        w2f[i] = ldf<BF>(w2, i);
    } else if (idx < 64512 + 784 + PDIM) {
        int p = idx - 64512 - 784;
        float inv_std = ldf<BF>(g, p) / sqrtf(ldf<BF>(vr, p) + 1e-3f);
        scale[p] = inv_std;
        shift[p] = ldf<BF>(bt, p) - ldf<BF>(mn, p) * inv_std;
    }
}

// ---------------- conv1 3x3 + BN + ReLU -> feat1 (fp32, [b][p][pix]) ----
template<bool BF>
__global__ __launch_bounds__(256) void conv1_kernel(
    const void* x, const void* g, const float* __restrict__ wf1,
    const float* __restrict__ scale, const float* __restrict__ shift,
    float* __restrict__ feat1) {
    if (detect_bf16(g) != BF) return;
    int b = blockIdx.y;
    int pix = blockIdx.x * 256 + threadIdx.x;
    if (pix >= HWDIM) return;
    int y = pix / WDIM;
    int xq = pix - y * WDIM;

    bool vrr[3] = { y > 0, true, y < HDIM - 1 };
    bool vcc[3] = { xq > 0, true, xq < WDIM - 1 };
    bool vv[9];
    int off[9];
#pragma unroll
    for (int i = 0; i < 3; i++) {
#pragma unroll
        for (int j = 0; j < 3; j++) {
            vv[i * 3 + j] = vrr[i] && vcc[j];
            off[i * 3 + j] = (y + i - 1) * WDIM + (xq + j - 1);
        }
    }

    long basex = (long)b * CIN * HWDIM;
    float acc[PDIM];
#pragma unroll
    for (int p = 0; p < PDIM; p++) acc[p] = 0.f;

    for (int c = 0; c < CIN; c++) {
        long cb = basex + (long)c * HWDIM;
        float xv[9];
#pragma unroll
        for (int t = 0; t < 9; t++)
            xv[t] = vv[t] ? ldf<BF>(x, cb + off[t]) : 0.f;
        const float* wc = wf1 + c * 252;  // wave-uniform -> scalar loads
#pragma unroll
        for (int p = 0; p < PDIM; p++) {
#pragma unroll
            for (int t = 0; t < 9; t++)
                acc[p] = fmaf(xv[t], wc[p * 9 + t], acc[p]);
        }
    }

    long ob = (long)b * PDIM * HWDIM + pix;
#pragma unroll
    for (int p = 0; p < PDIM; p++) {
        float v = fmaf(acc[p], scale[p], shift[p]);
        feat1[ob + (long)p * HWDIM] = v > 0.f ? v : 0.f;
    }
}

// ---------------- conv2 1x1 -> feat2 (fp32, [b][p][pix]) ----------------
__global__ __launch_bounds__(256) void conv2_kernel(
    const float* __restrict__ feat1, const float* __restrict__ w2f,
    float* __restrict__ feat2) {
    int b = blockIdx.y;
    int pix = blockIdx.x * 256 + threadIdx.x;
    if (pix >= HWDIM) return;
    long base = (long)b * PDIM * HWDIM + pix;
    float fv[PDIM];
#pragma unroll
    for (int q = 0; q < PDIM; q++) fv[q] = feat1[base + (long)q * HWDIM];
#pragma unroll
    for (int p = 0; p < PDIM; p++) {
        float a = 0.f;
#pragma unroll
        for (int q = 0; q < PDIM; q++) a = fmaf(fv[q], w2f[p * 28 + q], a);
        feat2[base + (long)p * HWDIM] = a;
    }
}

// ---------------- rotated-grid PS bilinear sampler ----------------------
template<bool BF>
__global__ void sample_kernel(const void* boxes, const void* g,
                              const float* __restrict__ feat2, void* out) {
    if (detect_bf16(g) != BF) return;
    int idx = blockIdx.x * 256 + threadIdx.x;  // 8192 total
    int b = idx >> 11;
    int n = idx & 2047;
    long bb = ((long)b * NBOX + n) * 7;
    float xg = ldf<BF>(boxes, bb + 0);
    float yg = ldf<BF>(boxes, bb + 1);
    float wg = ldf<BF>(boxes, bb + 3);
    float lg = ldf<BF>(boxes, bb + 4);
    float rg = ldf<BF>(boxes, bb + 6);
    float ct = cosf(rg), st = sinf(rg);

    const float lx[4] = { -0.5f, -0.16666667f, 0.16666667f, 0.5f };
    const float ly[7] = { -0.5f, -0.33333334f, -0.16666667f, 0.f,
                           0.16666667f, 0.33333334f, 0.5f };
    float acc = 0.f;
#pragma unroll
    for (int p = 0; p < PDIM; p++) {
        int h = p / 7, w = p - (p / 7) * 7;
        float xx = lx[h] * wg;
        float yy = ly[w] * lg;
        float gx = (xx * ct + yy * st + xg) * 2.5f;               // GRID_OFF.x = 0
        float gy = (yy * ct - xx * st + yg + 40.f) * 2.5f;        // GRID_OFF.y = 40
        const float* img = feat2 + ((long)b * PDIM + p) * HWDIM;
        float x0 = floorf(gx), y0 = floorf(gy);
        float fx = gx - x0, fy = gy - y0;
        int xi = (int)x0, yi = (int)y0;
        bool vx0 = (xi >= 0) && (xi <= WDIM - 1);
        bool vx1 = (xi + 1 >= 0) && (xi + 1 <= WDIM - 1);
        bool vy0 = (yi >= 0) && (yi <= HDIM - 1);
        bool vy1 = (yi + 1 >= 0) && (yi + 1 <= HDIM - 1);
        float Ia = 0.f, Ib = 0.f, Ic = 0.f, Id = 0.f;
        if (vy0 && vx0) Ia = img[yi * WDIM + xi];
        if (vy1 && vx0) Ib = img[(yi + 1) * WDIM + xi];
        if (vy0 && vx1) Ic = img[yi * WDIM + xi + 1];
        if (vy1 && vx1) Id = img[(yi + 1) * WDIM + xi + 1];
        acc += (1.f - fx) * (1.f - fy) * Ia + (1.f - fx) * fy * Ib
             + fx * (1.f - fy) * Ic + fx * fy * Id;
    }
    float res = acc / 28.f;
    if (BF) ((__hip_bfloat16*)out)[idx] = __float2bfloat16(res);
    else    ((float*)out)[idx] = res;
}

// ---------------- launch ------------------------------------------------
extern "C" void kernel_launch(void* const* d_in, const int* in_sizes, int n_in,
                              void* d_out, int out_size, void* d_ws, size_t ws_size,
                              hipStream_t stream) {
    const void* x     = d_in[0];
    const void* boxes = d_in[1];
    const void* w1    = d_in[2];
    const void* g     = d_in[3];
    const void* bt    = d_in[4];
    const void* mn    = d_in[5];
    const void* vr    = d_in[6];
    const void* w2    = d_in[7];

    char* ws = (char*)d_ws;
    float* wf1   = (float*)(ws + 0);              // 258048 B
    float* w2f   = (float*)(ws + 258048);         // 3136 B
    float* scale = (float*)(ws + 261184);         // 112 B
    float* shift = (float*)(ws + 261296);         // 112 B
    float* feat1 = (float*)(ws + 262144);         // 15,769,600 B
    float* feat2 = (float*)(ws + 262144 + 15769600);

    // prep (both dtype variants; mismatched one exits uniformly)
    prep_kernel<true ><<<256, 256, 0, stream>>>(w1, w2, g, bt, mn, vr, wf1, w2f, scale, shift);
    prep_kernel<false><<<256, 256, 0, stream>>>(w1, w2, g, bt, mn, vr, wf1, w2f, scale, shift);

    dim3 gconv(138, 4);
    conv1_kernel<true ><<<gconv, 256, 0, stream>>>(x, g, wf1, scale, shift, feat1);
    conv1_kernel<false><<<gconv, 256, 0, stream>>>(x, g, wf1, scale, shift, feat1);

    conv2_kernel<<<gconv, 256, 0, stream>>>(feat1, w2f, feat2);

    sample_kernel<true ><<<32, 256, 0, stream>>>(boxes, g, feat2, d_out);
    sample_kernel<false><<<32, 256, 0, stream>>>(boxes, g, feat2, d_out);
}

// Round 2
// 449.108 us; speedup vs baseline: 2.4305x; 2.4305x over previous
//
#include <hip/hip_runtime.h>
#include <hip/hip_bf16.h>

// PSWarpHead round 2: NHWC transpose + MFMA conv1 (9 shifted GEMMs) +
// fused conv2+rotated-grid PS bilinear sampler. Harness bf16-ifies tensors
// (confirmed round 1); dtype self-detection kept as insurance.

#define WDIM 176
#define HDIM 200
#define HWDIM 35200
#define CIN 256
#define PDIM 28
#define NBOX 2048

typedef __attribute__((ext_vector_type(8))) short bf16x8;
typedef __attribute__((ext_vector_type(4))) float floatx4;

__device__ __forceinline__ bool detect_bf16(const void* gamma) {
    return ((const unsigned short*)gamma)[0] == 0x3F80u;
}

template<bool BF>
__device__ __forceinline__ float ldf(const void* p, long i) {
    if (BF) {
        unsigned int u = ((unsigned int)((const unsigned short*)p)[i]) << 16;
        float f; __builtin_memcpy(&f, &u, 4); return f;
    } else {
        return ((const float*)p)[i];
    }
}

__device__ __forceinline__ unsigned short f2bf(float f) {
    unsigned int u; __builtin_memcpy(&u, &f, 4);
    unsigned int r = u + 0x7FFFu + ((u >> 16) & 1u);   // RNE
    return (unsigned short)(r >> 16);
}

// ------------- transpose: x [b][c][h][w] -> xT [b][h*w][c] (bf16) -------------
template<bool BF>
__global__ __launch_bounds__(256) void transpose_kernel(const void* x, const void* g,
                                                        unsigned short* __restrict__ xT) {
    if (detect_bf16(g) != BF) return;
    __shared__ unsigned short tile[32][80];   // 64 px used; stride 80 keeps 16B-aligned rows
    int b = blockIdx.z, c0 = blockIdx.y * 32, px0 = blockIdx.x * 64;
    int t = threadIdx.x;
    // load: thread -> 1 channel row, 8 px (16B bf16 / 32B fp32)
    int c_l = t >> 3, pxg = (t & 7) * 8;
    long src = ((long)(b * CIN + c0 + c_l)) * HWDIM + px0 + pxg;
    if (BF) {
        const ushort4* sp = (const ushort4*)((const unsigned short*)x + src);
        ushort4 a = sp[0], bq = sp[1];
        tile[c_l][pxg + 0] = a.x;  tile[c_l][pxg + 1] = a.y;
        tile[c_l][pxg + 2] = a.z;  tile[c_l][pxg + 3] = a.w;
        tile[c_l][pxg + 4] = bq.x; tile[c_l][pxg + 5] = bq.y;
        tile[c_l][pxg + 6] = bq.z; tile[c_l][pxg + 7] = bq.w;
    } else {
        const float4* sp = (const float4*)((const float*)x + src);
        float4 a = sp[0], bq = sp[1];
        tile[c_l][pxg + 0] = f2bf(a.x);  tile[c_l][pxg + 1] = f2bf(a.y);
        tile[c_l][pxg + 2] = f2bf(a.z);  tile[c_l][pxg + 3] = f2bf(a.w);
        tile[c_l][pxg + 4] = f2bf(bq.x); tile[c_l][pxg + 5] = f2bf(bq.y);
        tile[c_l][pxg + 6] = f2bf(bq.z); tile[c_l][pxg + 7] = f2bf(bq.w);
    }
    __syncthreads();
    // store: thread -> 1 px, 8 channels (16B contiguous in xT)
    int px_l = t >> 2, cg = (t & 3) * 8;
    ushort4 o0, o1;
    o0.x = tile[cg + 0][px_l]; o0.y = tile[cg + 1][px_l];
    o0.z = tile[cg + 2][px_l]; o0.w = tile[cg + 3][px_l];
    o1.x = tile[cg + 4][px_l]; o1.y = tile[cg + 5][px_l];
    o1.z = tile[cg + 6][px_l]; o1.w = tile[cg + 7][px_l];
    long dst = ((long)(b * HWDIM + px0 + px_l)) * CIN + c0 + cg;
    *(ushort4*)(xT + dst) = o0;
    *(ushort4*)(xT + dst + 4) = o1;
}

// ------------- prep: BwT[tap][n(32,pad0)][c] bf16, w2f fp32, BN fold -------------
template<bool BF>
__global__ void prep_kernel(const void* w1, const void* w2, const void* g, const void* bt,
                            const void* mn, const void* vr,
                            unsigned short* __restrict__ BwT, float* __restrict__ w2f,
                            float* __restrict__ scale, float* __restrict__ shift) {
    if (detect_bf16(g) != BF) return;
    int idx = blockIdx.x * 256 + threadIdx.x;
    if (idx < 9 * 32 * 256) {
        int tap = idx >> 13;              // /(32*256)
        int r = idx & 8191;
        int n = r >> 8, c = r & 255;
        unsigned short v = 0;
        if (n < PDIM) v = f2bf(ldf<BF>(w1, (long)n * 2304 + c * 9 + tap));
        BwT[idx] = v;
    } else if (idx < 73728 + 784) {
        int i = idx - 73728;
        w2f[i] = ldf<BF>(w2, i);
    } else if (idx < 73728 + 784 + 32) {
        int p = idx - 73728 - 784;
        if (p < PDIM) {
            float inv = ldf<BF>(g, p) / sqrtf(ldf<BF>(vr, p) + 1e-3f);
            scale[p] = inv;
            shift[p] = ldf<BF>(bt, p) - ldf<BF>(mn, p) * inv;
        } else { scale[p] = 0.f; shift[p] = 0.f; }
    }
}

// ------------- conv1: MFMA over 9 taps x 8 c-chunks; BN+ReLU epilogue -------------
// block = (b,y) row: 6 waves, wave w: m-tiles at px w*32 (+16); N=28 in 2 n-tiles.
// feat1 layout: [(b*HW + px)][32] fp32, q-contiguous (pad cols 28..31 = 0).
__global__ __launch_bounds__(384) void conv1_kernel(const unsigned short* __restrict__ xT,
                                                    const unsigned short* __restrict__ BwT,
                                                    const float* __restrict__ scale,
                                                    const float* __restrict__ shift,
                                                    float* __restrict__ feat1) {
    int y = blockIdx.x, b = blockIdx.y;
    int lane = threadIdx.x & 63, w = threadIdx.x >> 6;
    int nmt = (w == 5) ? 1 : 2;
    int lm = lane & 15, kg = lane >> 4;
    int pxb = w * 32;

    floatx4 acc[2][2] = {{{0.f,0.f,0.f,0.f},{0.f,0.f,0.f,0.f}},
                         {{0.f,0.f,0.f,0.f},{0.f,0.f,0.f,0.f}}};

    for (int tap = 0; tap < 9; tap++) {
        int dy = tap / 3 - 1, dx = tap % 3 - 1;
        int yp = y + dy;
        if (yp < 0 || yp >= HDIM) continue;      // block-uniform skip
        long rowbase = ((long)(b * HDIM + yp)) * WDIM;
        const unsigned short* bwt = BwT + (tap * 32 + lm) * 256 + kg * 8;
#pragma unroll 2
        for (int j = 0; j < 8; j++) {
            int cofs = j * 32;
            bf16x8 bfr0 = *(const bf16x8*)(bwt + cofs);
            bf16x8 bfr1 = *(const bf16x8*)(bwt + 16 * 256 + cofs);
#pragma unroll
            for (int mt = 0; mt < 2; mt++) {
                if (mt < nmt) {
                    int xp = pxb + mt * 16 + lm + dx;
                    bool valid = (xp >= 0) && (xp < WDIM);
                    int xpc = valid ? xp : 0;
                    const unsigned short* ap = xT + (rowbase + xpc) * CIN + cofs + kg * 8;
                    bf16x8 afr = *(const bf16x8*)ap;
                    if (!valid) afr = (bf16x8)0;
                    acc[mt][0] = __builtin_amdgcn_mfma_f32_16x16x32_bf16(afr, bfr0, acc[mt][0], 0, 0, 0);
                    acc[mt][1] = __builtin_amdgcn_mfma_f32_16x16x32_bf16(afr, bfr1, acc[mt][1], 0, 0, 0);
                }
            }
        }
    }

    long rowpix = (long)b * HWDIM + (long)y * WDIM;
#pragma unroll
    for (int mt = 0; mt < 2; mt++) {
        if (mt < nmt) {
#pragma unroll
            for (int nt = 0; nt < 2; nt++) {
                int n = nt * 16 + lm;            // C/D: col = lane&15
                float sc = scale[n], sh = shift[n];
#pragma unroll
                for (int r = 0; r < 4; r++) {
                    int px = pxb + mt * 16 + kg * 4 + r;   // row = (lane>>4)*4 + reg
                    float v = fmaf(acc[mt][nt][r], sc, sh);
                    feat1[(rowpix + px) * 32 + n] = v > 0.f ? v : 0.f;
                }
            }
        }
    }
}

// ------------- fused conv2(1x1) + rotated-grid PS bilinear sampler -------------
__device__ __forceinline__ float dot28(const float* __restrict__ row,
                                       const float* __restrict__ wv) {
    float s = 0.f;
#pragma unroll
    for (int i = 0; i < 7; i++) {
        float4 a = ((const float4*)row)[i];
        float4 b = ((const float4*)wv)[i];
        s = fmaf(a.x, b.x, s); s = fmaf(a.y, b.y, s);
        s = fmaf(a.z, b.z, s); s = fmaf(a.w, b.w, s);
    }
    return s;
}

template<bool BF>
__global__ __launch_bounds__(256) void sample_kernel(const void* boxes, const void* g,
                                                     const float* __restrict__ feat1,
                                                     const float* __restrict__ w2f,
                                                     void* out) {
    if (detect_bf16(g) != BF) return;
    int gid = blockIdx.x * 256 + threadIdx.x;
    int box = gid >> 5;          // 32 lanes per box, 8192 boxes
    int pl = gid & 31;
    int b = box >> 11;
    float val = 0.f;
    if (pl < PDIM) {
        long bb = (long)box * 7;
        float xg = ldf<BF>(boxes, bb + 0), yg = ldf<BF>(boxes, bb + 1);
        float wg = ldf<BF>(boxes, bb + 3), lg = ldf<BF>(boxes, bb + 4);
        float rg = ldf<BF>(boxes, bb + 6);
        float ct = cosf(rg), st = sinf(rg);
        const float lxv[4] = {-0.5f, -0.16666667f, 0.16666667f, 0.5f};
        const float lyv[7] = {-0.5f, -0.33333334f, -0.16666667f, 0.f,
                               0.16666667f, 0.33333334f, 0.5f};
        int h = pl / 7, ww = pl - (pl / 7) * 7;
        float xx = lxv[h] * wg;
        float yy = lyv[ww] * lg;
        float gx = (xx * ct + yy * st + xg) * 2.5f;           // GRID_OFF.x = 0
        float gy = (yy * ct - xx * st + yg + 40.f) * 2.5f;    // GRID_OFF.y = 40
        float x0 = floorf(gx), y0 = floorf(gy);
        float fx = gx - x0, fy = gy - y0;
        int xi = (int)x0, yi = (int)y0;
        const float* w2row = w2f + pl * PDIM;
        const float* base = feat1 + (long)b * HWDIM * 32;
        float Ia = 0.f, Ib = 0.f, Ic = 0.f, Id = 0.f;
        if (yi >= 0 && yi < HDIM) {
            if (xi >= 0 && xi < WDIM)         Ia = dot28(base + ((long)yi * WDIM + xi) * 32, w2row);
            if (xi + 1 >= 0 && xi + 1 < WDIM) Ic = dot28(base + ((long)yi * WDIM + xi + 1) * 32, w2row);
        }
        if (yi + 1 >= 0 && yi + 1 < HDIM) {
            if (xi >= 0 && xi < WDIM)         Ib = dot28(base + ((long)(yi + 1) * WDIM + xi) * 32, w2row);
            if (xi + 1 >= 0 && xi + 1 < WDIM) Id = dot28(base + ((long)(yi + 1) * WDIM + xi + 1) * 32, w2row);
        }
        val = (1.f - fx) * (1.f - fy) * Ia + (1.f - fx) * fy * Ib
            + fx * (1.f - fy) * Ic + fx * fy * Id;
    }
#pragma unroll
    for (int m = 16; m >= 1; m >>= 1) val += __shfl_xor(val, m, 64);
    if ((threadIdx.x & 31) == 0) {
        float res = val * (1.f / 28.f);
        if (BF) ((unsigned short*)out)[box] = f2bf(res);
        else    ((float*)out)[box] = res;
    }
}

// ------------- launch -------------
extern "C" void kernel_launch(void* const* d_in, const int* in_sizes, int n_in,
                              void* d_out, int out_size, void* d_ws, size_t ws_size,
                              hipStream_t stream) {
    const void* x     = d_in[0];
    const void* boxes = d_in[1];
    const void* w1    = d_in[2];
    const void* g     = d_in[3];
    const void* bt    = d_in[4];
    const void* mn    = d_in[5];
    const void* vr    = d_in[6];
    const void* w2    = d_in[7];

    char* ws = (char*)d_ws;
    unsigned short* xT  = (unsigned short*)ws;                 // 72,089,600 B
    float* feat1        = (float*)(ws + 72089600);             // 18,022,400 B
    unsigned short* BwT = (unsigned short*)(ws + 90112000);    //    147,456 B
    float* w2f          = (float*)(ws + 90259456);             //      3,136 B
    float* scale        = (float*)(ws + 90262592);             //        128 B
    float* shift        = (float*)(ws + 90262720);             //        128 B

    transpose_kernel<true ><<<dim3(550, 8, 4), 256, 0, stream>>>(x, g, xT);
    transpose_kernel<false><<<dim3(550, 8, 4), 256, 0, stream>>>(x, g, xT);

    prep_kernel<true ><<<292, 256, 0, stream>>>(w1, w2, g, bt, mn, vr, BwT, w2f, scale, shift);
    prep_kernel<false><<<292, 256, 0, stream>>>(w1, w2, g, bt, mn, vr, BwT, w2f, scale, shift);

    conv1_kernel<<<dim3(HDIM, 4), 384, 0, stream>>>(xT, BwT, scale, shift, feat1);

    sample_kernel<true ><<<1024, 256, 0, stream>>>(boxes, g, feat1, w2f, d_out);
    sample_kernel<false><<<1024, 256, 0, stream>>>(boxes, g, feat1, w2f, d_out);
}

// Round 6
// 435.732 us; speedup vs baseline: 2.5051x; 1.0307x over previous
//
#include <hip/hip_runtime.h>
#include <hip/hip_bf16.h>

// PSWarpHead round 6. ALL tensors FP32 (rounds 4/5 NaN forensics: fp32 boxes
// read as bf16 -> cosf(Inf) -> NaN; rounds 1-2 passed via the fp32 template
// path). Pipeline:
//   transpose: fp32 x [b][c][hw] -> bf16 xT [b][hw][c]   (round-2-validated)
//   conv1: MFMA 16x16x32 bf16, c-chunk-outer/tap-inner (L2 reuse fix)
//   fused conv2 + rotated-grid PS bilinear sampler (fp32 in/out)
// feat1 fp32 [px][32]. ws 90.26 MB (round-2 proven).

#define WDIM 176
#define HDIM 200
#define HWDIM 35200
#define CIN 256
#define PDIM 28
#define NBOX 2048

typedef __attribute__((ext_vector_type(8))) short bf16x8;
typedef __attribute__((ext_vector_type(4))) float floatx4;

__device__ __forceinline__ unsigned short f2bf(float f) {
    unsigned int u; __builtin_memcpy(&u, &f, 4);
    unsigned int r = u + 0x7FFFu + ((u >> 16) & 1u);   // RNE
    return (unsigned short)(r >> 16);
}

// ---------- transpose: fp32 x [b][c][hw] -> bf16 xT [b][hw][c] ----------
__global__ __launch_bounds__(256) void transpose_kernel(const float* __restrict__ x,
                                                        unsigned short* __restrict__ xT) {
    __shared__ unsigned short tile[32][80];
    int b = blockIdx.z, c0 = blockIdx.y * 32, px0 = blockIdx.x * 64;
    int t = threadIdx.x;
    int c_l = t >> 3, pxg = (t & 7) * 8;
    const float* sp = x + (long)(b * CIN + c0 + c_l) * HWDIM + px0 + pxg;
    float4 a = ((const float4*)sp)[0], bq = ((const float4*)sp)[1];
    tile[c_l][pxg + 0] = f2bf(a.x);  tile[c_l][pxg + 1] = f2bf(a.y);
    tile[c_l][pxg + 2] = f2bf(a.z);  tile[c_l][pxg + 3] = f2bf(a.w);
    tile[c_l][pxg + 4] = f2bf(bq.x); tile[c_l][pxg + 5] = f2bf(bq.y);
    tile[c_l][pxg + 6] = f2bf(bq.z); tile[c_l][pxg + 7] = f2bf(bq.w);
    __syncthreads();
    int px_l = t >> 2, cg = (t & 3) * 8;
    ushort4 o0, o1;
    o0.x = tile[cg + 0][px_l]; o0.y = tile[cg + 1][px_l];
    o0.z = tile[cg + 2][px_l]; o0.w = tile[cg + 3][px_l];
    o1.x = tile[cg + 4][px_l]; o1.y = tile[cg + 5][px_l];
    o1.z = tile[cg + 6][px_l]; o1.w = tile[cg + 7][px_l];
    long dst = (long)(b * HWDIM + px0 + px_l) * CIN + c0 + cg;
    *(ushort4*)(xT + dst) = o0;
    *(ushort4*)(xT + dst + 4) = o1;
}

// ---------- prep: BwT[tap][n(32,pad0)][c] bf16; w2f fp32; BN fold (fp32 in) ----------
__global__ void prep_kernel(const float* __restrict__ w1, const float* __restrict__ w2,
                            const float* __restrict__ g, const float* __restrict__ bt,
                            const float* __restrict__ mn, const float* __restrict__ vr,
                            unsigned short* __restrict__ BwT, float* __restrict__ w2f,
                            float* __restrict__ scale, float* __restrict__ shift) {
    int idx = blockIdx.x * 256 + threadIdx.x;
    if (idx < 9 * 32 * 256) {
        int tap = idx >> 13;
        int r = idx & 8191;
        int n = r >> 8, c = r & 255;
        BwT[idx] = (n < PDIM) ? f2bf(w1[n * 2304 + c * 9 + tap]) : (unsigned short)0;
    } else if (idx < 73728 + 784) {
        int i = idx - 73728;
        w2f[i] = w2[i];
    } else if (idx < 73728 + 784 + 32) {
        int p = idx - 73728 - 784;
        if (p < PDIM) {
            float inv = g[p] / sqrtf(vr[p] + 1e-3f);
            scale[p] = inv;
            shift[p] = bt[p] - mn[p] * inv;
        } else { scale[p] = 0.f; shift[p] = 0.f; }
    }
}

// ---------- conv1: MFMA, c-chunk-outer/tap-inner (same loads/MFMAs as r2, reordered) ----------
// block = (b,y) row: 6 waves, wave w -> px [w*32, w*32+32) (wave 5: 16 px).
__global__ __launch_bounds__(384) void conv1_kernel(const unsigned short* __restrict__ xT,
                                                    const unsigned short* __restrict__ BwT,
                                                    const float* __restrict__ scale,
                                                    const float* __restrict__ shift,
                                                    float* __restrict__ feat1) {
    int y = blockIdx.x, b = blockIdx.y;
    int lane = threadIdx.x & 63, w = threadIdx.x >> 6;
    int nmt = (w == 5) ? 1 : 2;
    int lm = lane & 15, kg = lane >> 4;
    int pxb = w * 32;

    // hoisted per-(mt, dx) lane column + validity
    int  xcol[2][3];
    bool xval[2][3];
#pragma unroll
    for (int mt = 0; mt < 2; mt++) {
#pragma unroll
        for (int d = 0; d < 3; d++) {
            int xp = pxb + mt * 16 + lm + (d - 1);
            bool v = (xp >= 0) && (xp < WDIM);
            xval[mt][d] = v;
            xcol[mt][d] = v ? xp : 0;
        }
    }

    floatx4 acc[2][2] = {{{0.f,0.f,0.f,0.f},{0.f,0.f,0.f,0.f}},
                         {{0.f,0.f,0.f,0.f},{0.f,0.f,0.f,0.f}}};

    for (int j = 0; j < 8; j++) {
        int cofs = j * 32 + kg * 8;
#pragma unroll
        for (int tap = 0; tap < 9; tap++) {
            int dy = tap / 3 - 1, d = tap % 3;
            int yp = y + dy;
            if (yp < 0 || yp >= HDIM) continue;          // block-uniform
            long rowpx = (long)(b * HDIM + yp) * WDIM;
            const unsigned short* bp = BwT + ((tap * 32 + lm) << 8) + cofs;
            bf16x8 b0 = *(const bf16x8*)bp;
            bf16x8 b1 = *(const bf16x8*)(bp + 4096);     // n-tile 1
#pragma unroll
            for (int mt = 0; mt < 2; mt++) {
                if (mt < nmt) {
                    const unsigned short* ap = xT + (rowpx + xcol[mt][d]) * CIN + cofs;
                    bf16x8 afr = *(const bf16x8*)ap;
                    if (!xval[mt][d]) afr = (bf16x8)0;
                    acc[mt][0] = __builtin_amdgcn_mfma_f32_16x16x32_bf16(afr, b0, acc[mt][0], 0, 0, 0);
                    acc[mt][1] = __builtin_amdgcn_mfma_f32_16x16x32_bf16(afr, b1, acc[mt][1], 0, 0, 0);
                }
            }
        }
    }

    // epilogue: C/D col = lane&15 (=n), row = (lane>>4)*4 + reg (=px offset)
    long rowpix = (long)b * HWDIM + (long)y * WDIM;
#pragma unroll
    for (int mt = 0; mt < 2; mt++) {
        if (mt < nmt) {
#pragma unroll
            for (int nt = 0; nt < 2; nt++) {
                int n = nt * 16 + lm;
                float sc = scale[n], sh = shift[n];
#pragma unroll
                for (int r = 0; r < 4; r++) {
                    int px = pxb + mt * 16 + kg * 4 + r;
                    float v = fmaf(acc[mt][nt][r], sc, sh);
                    feat1[(rowpix + px) * 32 + n] = v > 0.f ? v : 0.f;
                }
            }
        }
    }
}

// ---------- fused conv2(1x1) + PS bilinear sampler (fp32 boxes/out) ----------
__device__ __forceinline__ float dot28(const float* __restrict__ row,
                                       const float* __restrict__ wv) {
    float s = 0.f;
#pragma unroll
    for (int i = 0; i < 7; i++) {
        float4 a = ((const float4*)row)[i];
        float4 b = ((const float4*)wv)[i];
        s = fmaf(a.x, b.x, s); s = fmaf(a.y, b.y, s);
        s = fmaf(a.z, b.z, s); s = fmaf(a.w, b.w, s);
    }
    return s;
}

__global__ __launch_bounds__(256) void sample_kernel(const float* __restrict__ boxes,
                                                     const float* __restrict__ feat1,
                                                     const float* __restrict__ w2f,
                                                     float* __restrict__ out) {
    int gid = blockIdx.x * 256 + threadIdx.x;
    int box = gid >> 5;              // 32 lanes per box
    int pl = gid & 31;
    int b = box >> 11;
    float val = 0.f;
    if (pl < PDIM) {
        long bb = (long)box * 7;
        float xg = boxes[bb + 0], yg = boxes[bb + 1];
        float wg = boxes[bb + 3], lg = boxes[bb + 4];
        float rg = boxes[bb + 6];
        float ct = cosf(rg), st = sinf(rg);
        const float lxv[4] = {-0.5f, -0.16666667f, 0.16666667f, 0.5f};
        const float lyv[7] = {-0.5f, -0.33333334f, -0.16666667f, 0.f,
                               0.16666667f, 0.33333334f, 0.5f};
        int h = pl / 7, ww = pl - (pl / 7) * 7;
        float xx = lxv[h] * wg;
        float yy = lyv[ww] * lg;
        float gx = (xx * ct + yy * st + xg) * 2.5f;           // GRID_OFF.x = 0
        float gy = (yy * ct - xx * st + yg + 40.f) * 2.5f;    // GRID_OFF.y = 40
        float x0 = floorf(gx), y0 = floorf(gy);
        float fx = gx - x0, fy = gy - y0;
        int xi = (int)x0, yi = (int)y0;
        const float* w2row = w2f + pl * PDIM;
        const float* base = feat1 + (long)b * HWDIM * 32;
        float Ia = 0.f, Ib = 0.f, Ic = 0.f, Id = 0.f;
        if (yi >= 0 && yi < HDIM) {
            if (xi >= 0 && xi < WDIM)         Ia = dot28(base + ((long)yi * WDIM + xi) * 32, w2row);
            if (xi + 1 >= 0 && xi + 1 < WDIM) Ic = dot28(base + ((long)yi * WDIM + xi + 1) * 32, w2row);
        }
        if (yi + 1 >= 0 && yi + 1 < HDIM) {
            if (xi >= 0 && xi < WDIM)         Ib = dot28(base + ((long)(yi + 1) * WDIM + xi) * 32, w2row);
            if (xi + 1 >= 0 && xi + 1 < WDIM) Id = dot28(base + ((long)(yi + 1) * WDIM + xi + 1) * 32, w2row);
        }
        val = (1.f - fx) * (1.f - fy) * Ia + (1.f - fx) * fy * Ib
            + fx * (1.f - fy) * Ic + fx * fy * Id;
    }
#pragma unroll
    for (int m = 16; m >= 1; m >>= 1) val += __shfl_xor(val, m, 64);
    if ((threadIdx.x & 31) == 0) {
        out[box] = val * (1.f / 28.f);
    }
}

// ---------- launch ----------
extern "C" void kernel_launch(void* const* d_in, const int* in_sizes, int n_in,
                              void* d_out, int out_size, void* d_ws, size_t ws_size,
                              hipStream_t stream) {
    const float* x     = (const float*)d_in[0];
    const float* boxes = (const float*)d_in[1];
    const float* w1    = (const float*)d_in[2];
    const float* g     = (const float*)d_in[3];
    const float* bt    = (const float*)d_in[4];
    const float* mn    = (const float*)d_in[5];
    const float* vr    = (const float*)d_in[6];
    const float* w2    = (const float*)d_in[7];
    float* out = (float*)d_out;

    char* ws = (char*)d_ws;
    unsigned short* xT  = (unsigned short*)ws;                 // 72,089,600 B
    float* feat1        = (float*)(ws + 72089600);             // 18,022,400 B
    unsigned short* BwT = (unsigned short*)(ws + 90112000);    //    147,456 B
    float* w2f          = (float*)(ws + 90259456);             //      3,136 B
    float* scale        = (float*)(ws + 90262592);             //        128 B
    float* shift        = (float*)(ws + 90262720);             //        128 B

    transpose_kernel<<<dim3(550, 8, 4), 256, 0, stream>>>(x, xT);
    prep_kernel<<<292, 256, 0, stream>>>(w1, w2, g, bt, mn, vr, BwT, w2f, scale, shift);
    conv1_kernel<<<dim3(HDIM, 4), 384, 0, stream>>>(xT, BwT, scale, shift, feat1);
    sample_kernel<<<1024, 256, 0, stream>>>(boxes, feat1, w2f, out);
}